// Round 3
// baseline (144.010 us; speedup 1.0000x reference)
//
#include <hip/hip_runtime.h>

// EmotionCaps dynamic routing (fp32 I/O):
// u: [B=64, N=1024, I=64] f32; W: [N=1024, E=8, O=32, I=64] f32
// out: v [B=64, E=8, O=32] f32
//
// Structure (5 dispatches — kernel boundaries are the only cross-block sync;
// measured dead ends: grid.sync 110us/sync (r3), 64-block fusion 87us (r6),
// threadfence+counter 190us/pass (r7); uh2 packed layout neutral-to-worse
// (r1/r2 this session: 146/141 vs 135 baseline)):
//   k_uhat   : u_hat bf16 (row-major [b][n][eo]) via 16x16x32 bf16 MFMA.
//   k_route 0: c=1/8            -> partial p0[chunk][b][eo]   (NO atomics)
//   k_route 1: v0=squash(sum p0)-> logits=uh.v0 -> partial p1
//   k_route 2: v01=v0+v1        -> logits=uh.v01-> partial p2
//   k_out    : out = squash(sum p2)
// Logit identity b2 = uh.(v0+v1) verified rounds 4-7 (absmax stable 0.0039).
//
// THIS ROUND (single change vs the proven 134.9us round-0 kernel):
// atomic-free routing. Old: 524K device-scope fp32 atomicAdds/pass onto a
// 64KB buffer (32 adds/address; cross-XCD arbitration suspected ~10us/pass).
// New: each block stores its LDS-reduced partial to p[chunk][b][eo]
// (2MB/pass, fully overwritten -> poison-safe, no zero-init kernel work);
// the CONSUMER reduces the 32 chunk-slices cooperatively (32 coalesced 1KB
// reads/block from an L2/L3-hot 2MB buffer -> LDS -> verified squash4 path).
// Summation order: fixed 4-accumulator tree (>= atomic accuracy).

#define B_  64
#define N_  1024
#define I_  64
#define E_  8
#define O_  32
#define EO_ 256
#define PAD_ 72

typedef __bf16 bf16x8 __attribute__((ext_vector_type(8)));
typedef __bf16 bf16x4v __attribute__((ext_vector_type(4)));
typedef float  f32x4  __attribute__((ext_vector_type(4)));

__device__ __forceinline__ float bf2f(unsigned int h) {
    unsigned int x = (h & 0xffffu) << 16;
    return __builtin_bit_cast(float, x);
}
__device__ __forceinline__ void cvt_store4(unsigned short* dst, float4 q) {
    bf16x4v v;
    v[0] = (__bf16)q.x; v[1] = (__bf16)q.y; v[2] = (__bf16)q.z; v[3] = (__bf16)q.w;
    *(bf16x4v*)dst = v;
}
__device__ __forceinline__ bf16x8 cvt8(const float* __restrict__ p) {
    float4 q0 = *(const float4*)p;
    float4 q1 = *(const float4*)(p + 4);
    bf16x8 a;
    a[0] = (__bf16)q0.x; a[1] = (__bf16)q0.y; a[2] = (__bf16)q0.z; a[3] = (__bf16)q0.w;
    a[4] = (__bf16)q1.x; a[5] = (__bf16)q1.y; a[6] = (__bf16)q1.z; a[7] = (__bf16)q1.w;
    return a;
}
// squash over the 32-elem o-group; lane l holds s[4l..4l+3] of its e-group
// (8 lanes x 4). shfl 1,2,4 stays inside the 8-lane e-group.
__device__ __forceinline__ float4 squash4(float4 s4) {
    float sq = s4.x * s4.x + s4.y * s4.y + s4.z * s4.z + s4.w * s4.w;
    sq += __shfl_xor(sq, 1);
    sq += __shfl_xor(sq, 2);
    sq += __shfl_xor(sq, 4);
    float nrm = sqrtf(sq);
    float sc = sq / ((1.f + sq) * (nrm + 1e-8f));
    return make_float4(sc * s4.x, sc * s4.y, sc * s4.z, sc * s4.w);
}

// ---------------------------------------------------------------------------
// K1: one block per n. D[64b x 256eo] = u[:,n,:] . W[n]^T via 16x16x32 bf16
// MFMA (fragment layouts verified rounds 3-7). u staged in LDS (A-frags);
// W frags streamed from global; D transposed through the SAME LDS buffer
// (union: 33792 B -> 4 blocks/CU) for coalesced uint2 stores.
// VERBATIM round-0 (proven 134.9us) except: no s-buffer zeroing (the
// partial-sum scheme overwrites everything, poison-safe).
// ---------------------------------------------------------------------------
__global__ __launch_bounds__(256) void k_uhat(const float* __restrict__ u,
                                              const float* __restrict__ W,
                                              unsigned short* __restrict__ uh) {
    const int n = blockIdx.x;
    const int t = threadIdx.x;
    const int w = t >> 6, l = t & 63;
    const int m16 = l & 15, g = l >> 4;

    __shared__ __align__(16) unsigned short sh[B_ * 264];   // 33792 B (union)
    unsigned short* ul = sh;        // phase 1: u tile [B_][PAD_]
    unsigned short* Dt = sh;        // phase 2: D tile [B_][264]

#pragma unroll
    for (int j = 0; j < 4; ++j) {
        int idx = j * 256 + t;
        int b = idx >> 4, c = idx & 15;
        float4 q = *(const float4*)(u + (size_t)b * (N_ * I_) + n * I_ + c * 4);
        cvt_store4(&ul[b * PAD_ + c * 4], q);
    }
    __syncthreads();

    bf16x8 afr[4][2];   // A[m=lane&15][k=(lane>>4)*8+j]
#pragma unroll
    for (int mt = 0; mt < 4; ++mt)
#pragma unroll
        for (int ks = 0; ks < 2; ++ks)
            afr[mt][ks] = *(const bf16x8*)&ul[(mt * 16 + m16) * PAD_ + ks * 32 + g * 8];
    __syncthreads();    // all waves done reading ul; sh now reusable as Dt

    f32x4 acc[4][4];
#pragma unroll
    for (int nt = 0; nt < 4; ++nt)
#pragma unroll
        for (int mt = 0; mt < 4; ++mt)
            acc[nt][mt] = (f32x4){0.f, 0.f, 0.f, 0.f};

    const float* Wn = W + (size_t)n * (EO_ * I_);
#pragma unroll
    for (int nt = 0; nt < 4; ++nt) {
        const int eo = w * 64 + nt * 16 + m16;
        const float* wp = Wn + (size_t)eo * I_ + g * 8;
        bf16x8 b0 = cvt8(wp);
        bf16x8 b1 = cvt8(wp + 32);
#pragma unroll
        for (int mt = 0; mt < 4; ++mt) {
            acc[nt][mt] = __builtin_amdgcn_mfma_f32_16x16x32_bf16(afr[mt][0], b0, acc[nt][mt], 0, 0, 0);
            acc[nt][mt] = __builtin_amdgcn_mfma_f32_16x16x32_bf16(afr[mt][1], b1, acc[nt][mt], 0, 0, 0);
        }
    }

    // D lane map: col=lane&15, row=(lane>>4)*4+reg -> LDS transpose (hw cvt)
#pragma unroll
    for (int nt = 0; nt < 4; ++nt) {
        const int col = w * 64 + nt * 16 + m16;
#pragma unroll
        for (int mt = 0; mt < 4; ++mt)
#pragma unroll
            for (int r = 0; r < 4; ++r) {
                __bf16 hv = (__bf16)acc[nt][mt][r];
                Dt[(mt * 16 + g * 4 + r) * 264 + col] =
                    __builtin_bit_cast(unsigned short, hv);
            }
    }
    __syncthreads();
#pragma unroll
    for (int r = 0; r < 16; ++r) {
        const int row = r * 4 + w;
        uint2 q = *(const uint2*)&Dt[row * 264 + l * 4];
        *(uint2*)(uh + (size_t)row * (N_ * EO_) + (size_t)n * EO_ + l * 4) = q;
    }
}

// ---------------------------------------------------------------------------
// K2: one routing pass. 2048 blocks = (b, chunk of 32 n); wave handles 8 n;
// lane l owns eo = 4l..4l+3 (e = l>>3). Shuffle math verified rounds 2-7:
// dot over o = shfl 1,2,4; softmax over E = shfl 8,16,32.
// it>=1: s0 (and s1) recovered by a cooperative 32-slice reduce of the
// partial buffers (coalesced 1KB reads, L2/L3-hot) into LDS, then the
// verified squash4 path. Output: ONE plain store per thread into
// pout[chunk][b][eo] — zero atomics.
// ---------------------------------------------------------------------------
__global__ __launch_bounds__(256) void k_route(const unsigned short* __restrict__ uh,
                                               const float* __restrict__ p0,
                                               const float* __restrict__ p1,
                                               float* __restrict__ pout,
                                               int it) {
    const int blk = blockIdx.x;
    const int b = blk >> 5, chunk = blk & 31;
    const int t = threadIdx.x, wave = t >> 6, l = t & 63;

    const unsigned short* base = uh + (size_t)b * (N_ * EO_)
                                    + (size_t)(chunk * 32 + wave * 8) * EO_ + 4 * l;
    float x[8][4];
    float c[8];

    __shared__ __align__(16) float sv[2][EO_];     // reduced s0 / s1

    if (it == 0) {
#pragma unroll
        for (int nn = 0; nn < 8; ++nn) {
            uint2 p = *(const uint2*)(base + nn * EO_);
            x[nn][0] = bf2f(p.x); x[nn][1] = bf2f(p.x >> 16);
            x[nn][2] = bf2f(p.y); x[nn][3] = bf2f(p.y >> 16);
            c[nn] = 0.125f;
        }
    } else {
        // cooperative slice-reduce: s0[b][t] = sum_ch p0[ch][b][t]
        {
            float a0 = 0.f, a1 = 0.f, a2 = 0.f, a3 = 0.f;
            const float* pp = p0 + b * EO_ + t;
#pragma unroll
            for (int ch = 0; ch < 32; ch += 4) {
                a0 += pp[(size_t)(ch + 0) * (B_ * EO_)];
                a1 += pp[(size_t)(ch + 1) * (B_ * EO_)];
                a2 += pp[(size_t)(ch + 2) * (B_ * EO_)];
                a3 += pp[(size_t)(ch + 3) * (B_ * EO_)];
            }
            sv[0][t] = (a0 + a1) + (a2 + a3);
            if (it == 2) {
                float e0 = 0.f, e1 = 0.f, e2 = 0.f, e3 = 0.f;
                const float* qq = p1 + b * EO_ + t;
#pragma unroll
                for (int ch = 0; ch < 32; ch += 4) {
                    e0 += qq[(size_t)(ch + 0) * (B_ * EO_)];
                    e1 += qq[(size_t)(ch + 1) * (B_ * EO_)];
                    e2 += qq[(size_t)(ch + 2) * (B_ * EO_)];
                    e3 += qq[(size_t)(ch + 3) * (B_ * EO_)];
                }
                sv[1][t] = (e0 + e1) + (e2 + e3);
            }
        }
        __syncthreads();

        // recompute v (and v0+v1 for it==2): ~20 VALU, LDS-hot
        float4 v4 = squash4(*(const float4*)&sv[0][4 * l]);
        if (it == 2) {
            float4 v1 = squash4(*(const float4*)&sv[1][4 * l]);
            v4.x += v1.x; v4.y += v1.y; v4.z += v1.z; v4.w += v1.w;
        }
        float lg[8];
#pragma unroll
        for (int nn = 0; nn < 8; ++nn) {
            uint2 p = *(const uint2*)(base + nn * EO_);
            x[nn][0] = bf2f(p.x); x[nn][1] = bf2f(p.x >> 16);
            x[nn][2] = bf2f(p.y); x[nn][3] = bf2f(p.y >> 16);
            float pd = x[nn][0] * v4.x + x[nn][1] * v4.y
                     + x[nn][2] * v4.z + x[nn][3] * v4.w;
            pd += __shfl_xor(pd, 1);
            pd += __shfl_xor(pd, 2);
            pd += __shfl_xor(pd, 4);              // logit(n,e) in all 8 e-lanes
            lg[nn] = pd;
        }
        float mx[8];
#pragma unroll
        for (int nn = 0; nn < 8; ++nn) mx[nn] = lg[nn];
#pragma unroll
        for (int nn = 0; nn < 8; ++nn) mx[nn] = fmaxf(mx[nn], __shfl_xor(mx[nn], 8));
#pragma unroll
        for (int nn = 0; nn < 8; ++nn) mx[nn] = fmaxf(mx[nn], __shfl_xor(mx[nn], 16));
#pragma unroll
        for (int nn = 0; nn < 8; ++nn) mx[nn] = fmaxf(mx[nn], __shfl_xor(mx[nn], 32));
        float ex[8], sm[8];
#pragma unroll
        for (int nn = 0; nn < 8; ++nn) { ex[nn] = __expf(lg[nn] - mx[nn]); sm[nn] = ex[nn]; }
#pragma unroll
        for (int nn = 0; nn < 8; ++nn) sm[nn] += __shfl_xor(sm[nn], 8);
#pragma unroll
        for (int nn = 0; nn < 8; ++nn) sm[nn] += __shfl_xor(sm[nn], 16);
#pragma unroll
        for (int nn = 0; nn < 8; ++nn) sm[nn] += __shfl_xor(sm[nn], 32);
#pragma unroll
        for (int nn = 0; nn < 8; ++nn) c[nn] = ex[nn] * __builtin_amdgcn_rcpf(sm[nn]);
    }

    float a0 = 0.f, a1 = 0.f, a2 = 0.f, a3 = 0.f;
#pragma unroll
    for (int nn = 0; nn < 8; ++nn) {
        a0 = fmaf(c[nn], x[nn][0], a0); a1 = fmaf(c[nn], x[nn][1], a1);
        a2 = fmaf(c[nn], x[nn][2], a2); a3 = fmaf(c[nn], x[nn][3], a3);
    }

    __shared__ __align__(16) float red[4][EO_];
    *(float4*)&red[wave][4 * l] = make_float4(a0, a1, a2, a3);
    __syncthreads();
    // partial store: pout[chunk][b][eo] — coalesced 1KB per block, no atomics
    pout[((size_t)chunk * B_ + b) * EO_ + t] =
        red[0][t] + red[1][t] + red[2][t] + red[3][t];
}

// ---------------------------------------------------------------------------
// K3: out = squash(sum_ch p2[ch]). 64 blocks x 256 (t = eo; o-grp 32 lanes).
// ---------------------------------------------------------------------------
__global__ __launch_bounds__(256) void k_out(const float* __restrict__ p2,
                                             float* __restrict__ out) {
    const int b = blockIdx.x, t = threadIdx.x;
    float a0 = 0.f, a1 = 0.f, a2 = 0.f, a3 = 0.f;
    const float* pp = p2 + b * EO_ + t;
#pragma unroll
    for (int ch = 0; ch < 32; ch += 4) {
        a0 += pp[(size_t)(ch + 0) * (B_ * EO_)];
        a1 += pp[(size_t)(ch + 1) * (B_ * EO_)];
        a2 += pp[(size_t)(ch + 2) * (B_ * EO_)];
        a3 += pp[(size_t)(ch + 3) * (B_ * EO_)];
    }
    float sv = (a0 + a1) + (a2 + a3);
    float sq = sv * sv;
    sq += __shfl_xor(sq, 1);
    sq += __shfl_xor(sq, 2);
    sq += __shfl_xor(sq, 4);
    sq += __shfl_xor(sq, 8);
    sq += __shfl_xor(sq, 16);
    float nrm = sqrtf(sq);
    out[b * EO_ + t] = sq / ((1.f + sq) * (nrm + 1e-8f)) * sv;
}

extern "C" void kernel_launch(void* const* d_in, const int* in_sizes, int n_in,
                              void* d_out, int out_size, void* d_ws, size_t ws_size,
                              hipStream_t stream) {
    const float* u = (const float*)d_in[0];     // f32 [64,1024,64]
    const float* W = (const float*)d_in[1];     // f32 [1024,8,32,64]
    float* out = (float*)d_out;                 // f32 [64,8,32]

    char* ws = (char*)d_ws;
    unsigned short* uh = (unsigned short*)ws;    // 33,554,432 B  u_hat bf16
    float* p0 = (float*)(ws + 33554432);         // 2 MB  [32][64][256]
    float* p1 = p0 + 32 * B_ * EO_;              // 2 MB
    float* p2 = p1 + 32 * B_ * EO_;              // 2 MB   (total 39.8 MB < ws)

    k_uhat <<<dim3(N_),   dim3(256), 0, stream>>>(u, W, uh);
    k_route<<<dim3(2048), dim3(256), 0, stream>>>(uh, p0, p1, p0, 0);
    k_route<<<dim3(2048), dim3(256), 0, stream>>>(uh, p0, p1, p1, 1);
    k_route<<<dim3(2048), dim3(256), 0, stream>>>(uh, p0, p1, p2, 2);
    k_out  <<<dim3(B_),   dim3(256), 0, stream>>>(p2, out);
}

// Round 4
// 134.921 us; speedup vs baseline: 1.0674x; 1.0674x over previous
//
#include <hip/hip_runtime.h>

// EmotionCaps dynamic routing (fp32 I/O):
// u: [B=64, N=1024, I=64] f32; W: [N=1024, E=8, O=32, I=64] f32
// out: v [B=64, E=8, O=32] f32
//
// THIS ROUND: CALIBRATION. Byte-for-byte the proven round-0 kernel
// (134.9us, previous session). Rounds 1-3 of this session (uh2 layout,
// halved/zero atomics, partial-sum reduce) all landed 141-146 despite being
// structurally different -> suspect session offset / noise band, not real
// regressions. This run re-anchors the baseline within-session (rule #13:
// cross-session deltas <10% are not actionable).
//   dur ~135  -> variants genuinely regressed; epilogue A/B next.
//   dur ~140+ -> all r1-r3 deltas were noise; remaining time is fixed
//                harness/boundary cost; only >=20% structural changes can
//                register, else we are at the measurable ceiling.
//
// Structure (5 dispatches — kernel boundaries are the only cross-block sync;
// measured dead ends: grid.sync 110us/sync (r3), 64-block fusion 87us (r6),
// threadfence+counter 190us/pass (r7)):
//   k_uhat   : u_hat bf16 (32MB ws) via 16x16x32 bf16 MFMA; zeroes s0/s1/s2.
//   k_route 0: c=1/8            -> atomicAdd s0   (plain atomics: r2-proven)
//   k_route 1: v0=squash(s0)    -> logits=uh.v0   -> atomicAdd s1
//   k_route 2: v01=v0+v1        -> logits=uh.v01  -> atomicAdd s2
//   k_out    : out = squash(s2)
// Logit identity b2 = uh.(v0+v1) verified rounds 4-7 (absmax stable 0.0039).

#define B_  64
#define N_  1024
#define I_  64
#define E_  8
#define O_  32
#define EO_ 256
#define PAD_ 72

typedef __bf16 bf16x8 __attribute__((ext_vector_type(8)));
typedef __bf16 bf16x4v __attribute__((ext_vector_type(4)));
typedef float  f32x4  __attribute__((ext_vector_type(4)));

__device__ __forceinline__ float bf2f(unsigned int h) {
    unsigned int x = (h & 0xffffu) << 16;
    return __builtin_bit_cast(float, x);
}
__device__ __forceinline__ void cvt_store4(unsigned short* dst, float4 q) {
    bf16x4v v;
    v[0] = (__bf16)q.x; v[1] = (__bf16)q.y; v[2] = (__bf16)q.z; v[3] = (__bf16)q.w;
    *(bf16x4v*)dst = v;
}
__device__ __forceinline__ bf16x8 cvt8(const float* __restrict__ p) {
    float4 q0 = *(const float4*)p;
    float4 q1 = *(const float4*)(p + 4);
    bf16x8 a;
    a[0] = (__bf16)q0.x; a[1] = (__bf16)q0.y; a[2] = (__bf16)q0.z; a[3] = (__bf16)q0.w;
    a[4] = (__bf16)q1.x; a[5] = (__bf16)q1.y; a[6] = (__bf16)q1.z; a[7] = (__bf16)q1.w;
    return a;
}
// squash over the 32-elem o-group; lane l holds s[4l..4l+3] of its e-group
// (8 lanes x 4). shfl 1,2,4 stays inside the 8-lane e-group.
__device__ __forceinline__ float4 squash4(float4 s4) {
    float sq = s4.x * s4.x + s4.y * s4.y + s4.z * s4.z + s4.w * s4.w;
    sq += __shfl_xor(sq, 1);
    sq += __shfl_xor(sq, 2);
    sq += __shfl_xor(sq, 4);
    float nrm = sqrtf(sq);
    float sc = sq / ((1.f + sq) * (nrm + 1e-8f));
    return make_float4(sc * s4.x, sc * s4.y, sc * s4.z, sc * s4.w);
}

// ---------------------------------------------------------------------------
// K1: one block per n. D[64b x 256eo] = u[:,n,:] . W[n]^T via 16x16x32 bf16
// MFMA (fragment layouts verified rounds 3-7). u staged in LDS (A-frags);
// W frags streamed from global; D transposed through the SAME LDS buffer
// (union: 33792 B -> 4 blocks/CU) for coalesced uint2 stores.
// Epilogue uses hardware bf16 casts (RNE), not manual bit-twiddling.
// Blocks 0..2 zero s0/s1/s2 (workspace is poisoned each call).
// ---------------------------------------------------------------------------
__global__ __launch_bounds__(256) void k_uhat(const float* __restrict__ u,
                                              const float* __restrict__ W,
                                              unsigned short* __restrict__ uh,
                                              float* __restrict__ s012) {
    const int n = blockIdx.x;
    const int t = threadIdx.x;
    const int w = t >> 6, l = t & 63;
    const int m16 = l & 15, g = l >> 4;

    if (n < 3) {
        float* sz = s012 + n * (B_ * EO_);
#pragma unroll
        for (int i = 0; i < 64; ++i) sz[i * 256 + t] = 0.f;
    }

    __shared__ __align__(16) unsigned short sh[B_ * 264];   // 33792 B (union)
    unsigned short* ul = sh;        // phase 1: u tile [B_][PAD_]
    unsigned short* Dt = sh;        // phase 2: D tile [B_][264]

#pragma unroll
    for (int j = 0; j < 4; ++j) {
        int idx = j * 256 + t;
        int b = idx >> 4, c = idx & 15;
        float4 q = *(const float4*)(u + (size_t)b * (N_ * I_) + n * I_ + c * 4);
        cvt_store4(&ul[b * PAD_ + c * 4], q);
    }
    __syncthreads();

    bf16x8 afr[4][2];   // A[m=lane&15][k=(lane>>4)*8+j]
#pragma unroll
    for (int mt = 0; mt < 4; ++mt)
#pragma unroll
        for (int ks = 0; ks < 2; ++ks)
            afr[mt][ks] = *(const bf16x8*)&ul[(mt * 16 + m16) * PAD_ + ks * 32 + g * 8];
    __syncthreads();    // all waves done reading ul; sh now reusable as Dt

    f32x4 acc[4][4];
#pragma unroll
    for (int nt = 0; nt < 4; ++nt)
#pragma unroll
        for (int mt = 0; mt < 4; ++mt)
            acc[nt][mt] = (f32x4){0.f, 0.f, 0.f, 0.f};

    const float* Wn = W + (size_t)n * (EO_ * I_);
#pragma unroll
    for (int nt = 0; nt < 4; ++nt) {
        const int eo = w * 64 + nt * 16 + m16;
        const float* wp = Wn + (size_t)eo * I_ + g * 8;
        bf16x8 b0 = cvt8(wp);
        bf16x8 b1 = cvt8(wp + 32);
#pragma unroll
        for (int mt = 0; mt < 4; ++mt) {
            acc[nt][mt] = __builtin_amdgcn_mfma_f32_16x16x32_bf16(afr[mt][0], b0, acc[nt][mt], 0, 0, 0);
            acc[nt][mt] = __builtin_amdgcn_mfma_f32_16x16x32_bf16(afr[mt][1], b1, acc[nt][mt], 0, 0, 0);
        }
    }

    // D lane map: col=lane&15, row=(lane>>4)*4+reg -> LDS transpose (hw cvt)
#pragma unroll
    for (int nt = 0; nt < 4; ++nt) {
        const int col = w * 64 + nt * 16 + m16;
#pragma unroll
        for (int mt = 0; mt < 4; ++mt)
#pragma unroll
            for (int r = 0; r < 4; ++r) {
                __bf16 hv = (__bf16)acc[nt][mt][r];
                Dt[(mt * 16 + g * 4 + r) * 264 + col] =
                    __builtin_bit_cast(unsigned short, hv);
            }
    }
    __syncthreads();
#pragma unroll
    for (int r = 0; r < 16; ++r) {
        const int row = r * 4 + w;
        uint2 q = *(const uint2*)&Dt[row * 264 + l * 4];
        *(uint2*)(uh + (size_t)row * (N_ * EO_) + (size_t)n * EO_ + l * 4) = q;
    }
}

// ---------------------------------------------------------------------------
// K2: one routing pass. 2048 blocks = (b, chunk of 32 n); wave handles 8 n;
// lane l owns eo = 4l..4l+3 (e = l>>3). Shuffle math verified rounds 2-7:
// dot over o = shfl 1,2,4; softmax over E = shfl 8,16,32.
// it selects the v recomputation (from s0/s1, visible since prior dispatch
// completed) and the target accumulator. One atomicAdd per (b,eo) per block.
// ---------------------------------------------------------------------------
__global__ __launch_bounds__(256) void k_route(const unsigned short* __restrict__ uh,
                                               const float* __restrict__ s0,
                                               const float* __restrict__ s1,
                                               float* __restrict__ tgt,
                                               int it) {
    const int blk = blockIdx.x;
    const int b = blk >> 5, chunk = blk & 31;
    const int t = threadIdx.x, wave = t >> 6, l = t & 63;

    const unsigned short* base = uh + (size_t)b * (N_ * EO_)
                                    + (size_t)(chunk * 32 + wave * 8) * EO_ + 4 * l;
    float x[8][4];
    float c[8];

    if (it == 0) {
#pragma unroll
        for (int nn = 0; nn < 8; ++nn) {
            uint2 p = *(const uint2*)(base + nn * EO_);
            x[nn][0] = bf2f(p.x); x[nn][1] = bf2f(p.x >> 16);
            x[nn][2] = bf2f(p.y); x[nn][3] = bf2f(p.y >> 16);
            c[nn] = 0.125f;
        }
    } else {
        // recompute v (and v0+v1 for it==2) from s-buffers: ~20 VALU, L2-hot
        float4 v4 = squash4(*(const float4*)(s0 + b * EO_ + 4 * l));
        if (it == 2) {
            float4 v1 = squash4(*(const float4*)(s1 + b * EO_ + 4 * l));
            v4.x += v1.x; v4.y += v1.y; v4.z += v1.z; v4.w += v1.w;
        }
        float lg[8];
#pragma unroll
        for (int nn = 0; nn < 8; ++nn) {
            uint2 p = *(const uint2*)(base + nn * EO_);
            x[nn][0] = bf2f(p.x); x[nn][1] = bf2f(p.x >> 16);
            x[nn][2] = bf2f(p.y); x[nn][3] = bf2f(p.y >> 16);
            float pd = x[nn][0] * v4.x + x[nn][1] * v4.y
                     + x[nn][2] * v4.z + x[nn][3] * v4.w;
            pd += __shfl_xor(pd, 1);
            pd += __shfl_xor(pd, 2);
            pd += __shfl_xor(pd, 4);              // logit(n,e) in all 8 e-lanes
            lg[nn] = pd;
        }
        float mx[8];
#pragma unroll
        for (int nn = 0; nn < 8; ++nn) mx[nn] = lg[nn];
#pragma unroll
        for (int nn = 0; nn < 8; ++nn) mx[nn] = fmaxf(mx[nn], __shfl_xor(mx[nn], 8));
#pragma unroll
        for (int nn = 0; nn < 8; ++nn) mx[nn] = fmaxf(mx[nn], __shfl_xor(mx[nn], 16));
#pragma unroll
        for (int nn = 0; nn < 8; ++nn) mx[nn] = fmaxf(mx[nn], __shfl_xor(mx[nn], 32));
        float ex[8], sm[8];
#pragma unroll
        for (int nn = 0; nn < 8; ++nn) { ex[nn] = __expf(lg[nn] - mx[nn]); sm[nn] = ex[nn]; }
#pragma unroll
        for (int nn = 0; nn < 8; ++nn) sm[nn] += __shfl_xor(sm[nn], 8);
#pragma unroll
        for (int nn = 0; nn < 8; ++nn) sm[nn] += __shfl_xor(sm[nn], 16);
#pragma unroll
        for (int nn = 0; nn < 8; ++nn) sm[nn] += __shfl_xor(sm[nn], 32);
#pragma unroll
        for (int nn = 0; nn < 8; ++nn) c[nn] = ex[nn] * __builtin_amdgcn_rcpf(sm[nn]);
    }

    float a0 = 0.f, a1 = 0.f, a2 = 0.f, a3 = 0.f;
#pragma unroll
    for (int nn = 0; nn < 8; ++nn) {
        a0 = fmaf(c[nn], x[nn][0], a0); a1 = fmaf(c[nn], x[nn][1], a1);
        a2 = fmaf(c[nn], x[nn][2], a2); a3 = fmaf(c[nn], x[nn][3], a3);
    }

    __shared__ __align__(16) float red[4][EO_];
    *(float4*)&red[wave][4 * l] = make_float4(a0, a1, a2, a3);
    __syncthreads();
    atomicAdd(&tgt[b * EO_ + t], red[0][t] + red[1][t] + red[2][t] + red[3][t]);
}

// ---------------------------------------------------------------------------
// K3: out = squash(s2). 64 blocks x 256 (t = eo; o-group = 32 lanes).
// ---------------------------------------------------------------------------
__global__ __launch_bounds__(256) void k_out(const float* __restrict__ s2,
                                             float* __restrict__ out) {
    const int b = blockIdx.x, t = threadIdx.x;
    float sv = s2[b * EO_ + t];
    float sq = sv * sv;
    sq += __shfl_xor(sq, 1);
    sq += __shfl_xor(sq, 2);
    sq += __shfl_xor(sq, 4);
    sq += __shfl_xor(sq, 8);
    sq += __shfl_xor(sq, 16);
    float nrm = sqrtf(sq);
    out[b * EO_ + t] = sq / ((1.f + sq) * (nrm + 1e-8f)) * sv;
}

extern "C" void kernel_launch(void* const* d_in, const int* in_sizes, int n_in,
                              void* d_out, int out_size, void* d_ws, size_t ws_size,
                              hipStream_t stream) {
    const float* u = (const float*)d_in[0];     // f32 [64,1024,64]
    const float* W = (const float*)d_in[1];     // f32 [1024,8,32,64]
    float* out = (float*)d_out;                 // f32 [64,8,32]

    char* ws = (char*)d_ws;
    unsigned short* uh = (unsigned short*)ws;    // 33,554,432 B  u_hat bf16
    float* s0 = (float*)(ws + 33554432);         // 65,536 B
    float* s1 = (float*)(ws + 33620 * 1024);     // (33620*1024 = 34,426,880)
    float* s2 = (float*)(ws + 34492416);         // 65,536 B

    // contiguous s0|s1|s2 for the zeroing loop in k_uhat
    s1 = s0 + B_ * EO_;
    s2 = s1 + B_ * EO_;

    k_uhat <<<dim3(N_),   dim3(256), 0, stream>>>(u, W, uh, s0);
    k_route<<<dim3(2048), dim3(256), 0, stream>>>(uh, s0, s1, s0, 0);
    k_route<<<dim3(2048), dim3(256), 0, stream>>>(uh, s0, s1, s1, 1);
    k_route<<<dim3(2048), dim3(256), 0, stream>>>(uh, s0, s1, s2, 2);
    k_out  <<<dim3(B_),   dim3(256), 0, stream>>>(s2, out);
}